// Round 1
// baseline (92.900 us; speedup 1.0000x reference)
//
#include <hip/hip_runtime.h>

#define R 128
#define C 80
#define HH 28
#define WW 28
#define NPIX 784          // 28*28
#define BIGD (1 << 26)    // sentinel for "no opposite pixel in this row"

// One block per image (blocks 0..R-1: sigmoid(preds[b, labels[b]]); blocks
// R..2R-1: targets[b-R]). Computes the normalized squared distance field
// (field**2) for each pixel and stores it to distP / distT. Also stores the
// sigmoid-selected pred channel (p_sel) for the final error term.
__global__ __launch_bounds__(256) void edt_field_kernel(
    const float* __restrict__ preds,
    const float* __restrict__ targets,
    const int* __restrict__ labels,
    float* __restrict__ distP,   // [R, 784] field^2 of pred images
    float* __restrict__ distT,   // [R, 784] field^2 of target images
    float* __restrict__ p_sel,   // [R, 784] sigmoid-selected pred channel
    float* __restrict__ out)     // zeroed by block 0 (kernel C runs after)
{
    __shared__ unsigned fgrow[HH];        // fg mask bits per row (28 bits)
    __shared__ int rowd[2][HH][WW];       // min sq horiz dist to class-c pixel in row r, col x
    __shared__ int md2[NPIX];             // per-pixel min sq dist to opposite class
    __shared__ int redF[256], redB[256];  // max-reduce scratch
    __shared__ float invF, invB;
    __shared__ int s_uniform;

    const int tid = threadIdx.x;
    const int b = blockIdx.x;

    if (b == 0 && tid == 0) out[0] = 0.0f;   // kernel C (stream-ordered) atomicAdds into this

    if (tid < HH) fgrow[tid] = 0u;
    __syncthreads();

    const bool isPred = (b < R);
    const float* src;
    float* pstore = nullptr;
    if (isPred) {
        const int lab = labels[b];
        src = preds + ((size_t)b * C + (size_t)lab) * NPIX;
        pstore = p_sel + (size_t)b * NPIX;
    } else {
        src = targets + (size_t)(b - R) * NPIX;
    }

    // Load pixels, compute fg mask bits (fg = value > 0.5 after sigmoid for preds).
    for (int j = tid; j < NPIX; j += 256) {
        float v = src[j];
        float s;
        if (isPred) {
            s = 1.0f / (1.0f + expf(-v));
            pstore[j] = s;
        } else {
            s = v;
        }
        if (s > 0.5f) {
            atomicOr(&fgrow[j / WW], 1u << (j % WW));
        }
    }
    __syncthreads();

    // Build rowd[c][r][x]: min over columns kx with class(r,kx)==c of (x-kx)^2.
    // O(1) per entry via clz/ctz on the 28-bit row mask.
    for (int e = tid; e < 2 * NPIX; e += 256) {
        const int c = (e >= NPIX);
        const int rem = e - c * NPIX;
        const int r = rem / WW;
        const int x = rem - r * WW;
        const unsigned fr = fgrow[r];
        const unsigned w = c ? fr : (~fr & 0x0FFFFFFFu);
        int dv;
        if (w == 0u) {
            dv = BIGD;
        } else {
            const unsigned wl = w & ((2u << x) - 1u);  // bits 0..x
            const unsigned wr = w >> x;                // bits x..27 shifted to 0..
            const int dl = wl ? (x - (31 - __builtin_clz(wl))) : 10000;
            const int dr = wr ? __builtin_ctz(wr) : 10000;
            const int d = dl < dr ? dl : dr;
            dv = d * d;
        }
        rowd[c][r][x] = dv;
    }
    __syncthreads();

    // Per-pixel: min over 28 rows of dy^2 + rowd[opposite][r][x]; track per-class max.
    int localF = -1, localB = -1;
    for (int j = tid; j < NPIX; j += 256) {
        const int y = j / WW;
        const int x = j - y * WW;
        const int c = (fgrow[y] >> x) & 1;
        const int* rd = &rowd[c ^ 1][0][x];
        int m = 0x3FFFFFFF;
        #pragma unroll
        for (int r = 0; r < HH; ++r) {
            const int dy = y - r;
            const int cand = dy * dy + rd[r * WW];
            m = cand < m ? cand : m;
        }
        md2[j] = m;
        if (c) localF = m > localF ? m : localF;
        else   localB = m > localB ? m : localB;
    }
    redF[tid] = localF;
    redB[tid] = localB;
    __syncthreads();
    for (int s = 128; s > 0; s >>= 1) {
        if (tid < s) {
            redF[tid] = redF[tid + s] > redF[tid] ? redF[tid + s] : redF[tid];
            redB[tid] = redB[tid + s] > redB[tid] ? redB[tid + s] : redB[tid];
        }
        __syncthreads();
    }
    if (tid == 0) {
        const int mF = redF[0], mB = redB[0];
        if (mF < 0 || mB < 0) {   // uniform mask (or empty): field is identically 0
            s_uniform = 1; invF = 0.0f; invB = 0.0f;
        } else {
            s_uniform = 0;
            invF = 1.0f / (float)mF;   // field^2 = md2 / max_md2(same class)
            invB = 1.0f / (float)mB;
        }
    }
    __syncthreads();

    float* dst = isPred ? (distP + (size_t)b * NPIX)
                        : (distT + (size_t)(b - R) * NPIX);
    const int uni = s_uniform;
    for (int j = tid; j < NPIX; j += 256) {
        float fsq = 0.0f;
        if (!uni) {
            const int y = j / WW;
            const int x = j - y * WW;
            const int c = (fgrow[y] >> x) & 1;
            fsq = (float)md2[j] * (c ? invF : invB);
        }
        dst[j] = fsq;
    }
}

// One thread per pixel: serial cumulative sum over R samples, accumulate
// err*cum, wave-reduce, atomicAdd scaled partial into out[0].
__global__ __launch_bounds__(64) void reduce_kernel(
    const float* __restrict__ distP,
    const float* __restrict__ distT,
    const float* __restrict__ p_sel,
    const float* __restrict__ targets,
    float* __restrict__ out)
{
    const int px = blockIdx.x * 64 + threadIdx.x;
    float acc = 0.0f;
    if (px < NPIX) {
        float cum = 0.0f;
        for (int i = 0; i < R; ++i) {
            const size_t o = (size_t)i * NPIX + px;
            cum += distP[o] + distT[o];
            const float e = p_sel[o] - targets[o];
            acc += e * e * cum;
        }
    }
    #pragma unroll
    for (int off = 32; off > 0; off >>= 1)
        acc += __shfl_down(acc, off, 64);
    if (threadIdx.x == 0)
        atomicAdd(out, acc * (1.0f / ((float)R * (float)NPIX)));
}

extern "C" void kernel_launch(void* const* d_in, const int* in_sizes, int n_in,
                              void* d_out, int out_size, void* d_ws, size_t ws_size,
                              hipStream_t stream) {
    const float* preds = (const float*)d_in[0];
    const float* targets = (const float*)d_in[1];
    const int* labels = (const int*)d_in[2];
    float* out = (float*)d_out;

    float* ws = (float*)d_ws;
    float* distP = ws;                        // R*784 floats
    float* distT = ws + (size_t)R * NPIX;     // R*784 floats
    float* p_sel = ws + (size_t)2 * R * NPIX; // R*784 floats

    hipLaunchKernelGGL(edt_field_kernel, dim3(2 * R), dim3(256), 0, stream,
                       preds, targets, labels, distP, distT, p_sel, out);
    hipLaunchKernelGGL(reduce_kernel, dim3((NPIX + 63) / 64), dim3(64), 0, stream,
                       distP, distT, p_sel, targets, out);
}

// Round 2
// 92.394 us; speedup vs baseline: 1.0055x; 1.0055x over previous
//
#include <hip/hip_runtime.h>

#define R 128
#define C 80
#define HH 28
#define WW 28
#define NPIX 784          // 28*28
#define BIGD (1 << 26)    // sentinel for "no opposite pixel in this row"

// One block per image (blocks 0..R-1: sigmoid(preds[b, labels[b]]); blocks
// R..2R-1: targets[b-R]). Computes the normalized squared distance field
// (field**2) and stores it TRANSPOSED as [px][i] for coalesced phase-2 scans.
// Pred blocks also compute err = (sigmoid - target)^2, stored [px][i].
__global__ __launch_bounds__(256) void edt_field_kernel(
    const float* __restrict__ preds,
    const float* __restrict__ targets,
    const int* __restrict__ labels,
    float* __restrict__ distP_t,  // [784, R] field^2 of pred images (transposed)
    float* __restrict__ distT_t,  // [784, R] field^2 of target images (transposed)
    float* __restrict__ err_t,    // [784, R] (sigmoid - target)^2 (transposed)
    float* __restrict__ out)      // zeroed by block 0 (phase 2 runs after)
{
    __shared__ unsigned fgrow[HH];        // fg mask bits per row (28 bits)
    __shared__ int rowd[2][HH][WW];       // min sq horiz dist to class-c pixel in row r, col x
    __shared__ int md2[NPIX];             // per-pixel min sq dist to opposite class
    __shared__ int redF[256], redB[256];  // max-reduce scratch
    __shared__ float invF, invB;
    __shared__ int s_uniform;

    const int tid = threadIdx.x;
    const int b = blockIdx.x;

    if (b == 0 && tid == 0) out[0] = 0.0f;   // phase 2 (stream-ordered) atomicAdds into this

    if (tid < HH) fgrow[tid] = 0u;
    __syncthreads();

    const bool isPred = (b < R);
    const int rb = isPred ? b : (b - R);
    const float* src;
    const float* tgt = targets + (size_t)rb * NPIX;
    if (isPred) {
        const int lab = labels[b];
        src = preds + ((size_t)b * C + (size_t)lab) * NPIX;
    } else {
        src = tgt;
    }

    // Load pixels, compute fg mask bits; pred blocks also emit err^2 transposed.
    for (int j = tid; j < NPIX; j += 256) {
        float v = src[j];
        float s;
        if (isPred) {
            s = 1.0f / (1.0f + expf(-v));
            const float e = s - tgt[j];
            err_t[(size_t)j * R + b] = e * e;
        } else {
            s = v;
        }
        if (s > 0.5f) {
            atomicOr(&fgrow[j / WW], 1u << (j % WW));
        }
    }
    __syncthreads();

    // Build rowd[c][r][x]: min over columns kx with class(r,kx)==c of (x-kx)^2.
    // O(1) per entry via clz/ctz on the 28-bit row mask.
    for (int e = tid; e < 2 * NPIX; e += 256) {
        const int c = (e >= NPIX);
        const int rem = e - c * NPIX;
        const int r = rem / WW;
        const int x = rem - r * WW;
        const unsigned fr = fgrow[r];
        const unsigned w = c ? fr : (~fr & 0x0FFFFFFFu);
        int dv;
        if (w == 0u) {
            dv = BIGD;
        } else {
            const unsigned wl = w & ((2u << x) - 1u);  // bits 0..x
            const unsigned wr = w >> x;                // bits x..27 shifted to 0..
            const int dl = wl ? (x - (31 - __builtin_clz(wl))) : 10000;
            const int dr = wr ? __builtin_ctz(wr) : 10000;
            const int d = dl < dr ? dl : dr;
            dv = d * d;
        }
        rowd[c][r][x] = dv;
    }
    __syncthreads();

    // Per-pixel: min over 28 rows of dy^2 + rowd[opposite][r][x]; track per-class max.
    int localF = -1, localB = -1;
    for (int j = tid; j < NPIX; j += 256) {
        const int y = j / WW;
        const int x = j - y * WW;
        const int c = (fgrow[y] >> x) & 1;
        const int* rd = &rowd[c ^ 1][0][x];
        int m = 0x3FFFFFFF;
        #pragma unroll
        for (int r = 0; r < HH; ++r) {
            const int dy = y - r;
            const int cand = dy * dy + rd[r * WW];
            m = cand < m ? cand : m;
        }
        md2[j] = m;
        if (c) localF = m > localF ? m : localF;
        else   localB = m > localB ? m : localB;
    }
    redF[tid] = localF;
    redB[tid] = localB;
    __syncthreads();
    for (int s = 128; s > 0; s >>= 1) {
        if (tid < s) {
            redF[tid] = redF[tid + s] > redF[tid] ? redF[tid + s] : redF[tid];
            redB[tid] = redB[tid + s] > redB[tid] ? redB[tid + s] : redB[tid];
        }
        __syncthreads();
    }
    if (tid == 0) {
        const int mF = redF[0], mB = redB[0];
        if (mF < 0 || mB < 0) {   // uniform mask (or empty): field is identically 0
            s_uniform = 1; invF = 0.0f; invB = 0.0f;
        } else {
            s_uniform = 0;
            invF = 1.0f / (float)mF;   // field^2 = md2 / max_md2(same class)
            invB = 1.0f / (float)mB;
        }
    }
    __syncthreads();

    float* dst = isPred ? distP_t : distT_t;
    const int uni = s_uniform;
    for (int j = tid; j < NPIX; j += 256) {
        float fsq = 0.0f;
        if (!uni) {
            const int y = j / WW;
            const int x = j - y * WW;
            const int c = (fgrow[y] >> x) & 1;
            fsq = (float)md2[j] * (c ? invF : invB);
        }
        dst[(size_t)j * R + rb] = fsq;
    }
}

// One block per pixel, 128 threads = R lanes. Coalesced loads of the
// transposed arrays, shuffle-based inclusive scan over R, block reduce,
// one atomicAdd per block.
__global__ __launch_bounds__(128) void scan_reduce_kernel(
    const float* __restrict__ distP_t,
    const float* __restrict__ distT_t,
    const float* __restrict__ err_t,
    float* __restrict__ out)
{
    __shared__ float wsum;
    __shared__ float bacc[2];

    const int px = blockIdx.x;
    const int i = threadIdx.x;             // sample index in [0, R)
    const size_t o = (size_t)px * R + i;

    float cum = distP_t[o] + distT_t[o];
    const float e2 = err_t[o];

    // inclusive scan within wave64
    #pragma unroll
    for (int off = 1; off < 64; off <<= 1) {
        const float v = __shfl_up(cum, off, 64);
        if ((i & 63) >= off) cum += v;
    }
    if (i == 63) wsum = cum;               // wave 0 total
    __syncthreads();
    if (i >= 64) cum += wsum;              // wave 1 offset

    float acc = e2 * cum;
    #pragma unroll
    for (int off = 32; off > 0; off >>= 1)
        acc += __shfl_down(acc, off, 64);
    if ((i & 63) == 0) bacc[i >> 6] = acc;
    __syncthreads();
    if (i == 0)
        atomicAdd(out, (bacc[0] + bacc[1]) * (1.0f / ((float)R * (float)NPIX)));
}

extern "C" void kernel_launch(void* const* d_in, const int* in_sizes, int n_in,
                              void* d_out, int out_size, void* d_ws, size_t ws_size,
                              hipStream_t stream) {
    const float* preds = (const float*)d_in[0];
    const float* targets = (const float*)d_in[1];
    const int* labels = (const int*)d_in[2];
    float* out = (float*)d_out;

    float* ws = (float*)d_ws;
    float* distP_t = ws;                        // 784*R floats
    float* distT_t = ws + (size_t)R * NPIX;     // 784*R floats
    float* err_t   = ws + (size_t)2 * R * NPIX; // 784*R floats

    hipLaunchKernelGGL(edt_field_kernel, dim3(2 * R), dim3(256), 0, stream,
                       preds, targets, labels, distP_t, distT_t, err_t, out);
    hipLaunchKernelGGL(scan_reduce_kernel, dim3(NPIX), dim3(128), 0, stream,
                       distP_t, distT_t, err_t, out);
}